// Round 1
// baseline (46.753 us; speedup 1.0000x reference)
//
#include <hip/hip_runtime.h>

// Problem constants (match reference setup_inputs)
#define BATCH 2
#define NPART 4096
#define TI 256      // i-particles per block (1 per thread)
#define SEG 512     // j-particles per block (staged in LDS)
#define JSEGS (NPART / SEG)   // 8

// dq = p / m  (m broadcast over the 3 coords)
__global__ __launch_bounds__(256) void dq_kernel(const float* __restrict__ p,
                                                 const float* __restrict__ m,
                                                 float* __restrict__ dq, int n_elem) {
    int e = blockIdx.x * blockDim.x + threadIdx.x;
    if (e < n_elem) {
        dq[e] = p[e] / m[e / 3];
    }
}

// Lennard-Jones pair forces: dp[b,i,:] = sum_j coeff(i,j) * (q_i - q_j)
// coeff = 24*eps*inv_r2*s6*(2*s6-1), s6 = (sigma^2*inv_r2)^3, eps=sigma=1
// Grid: (JSEGS, NPART/TI, BATCH), block: TI=256 threads (one i each).
// Each block handles one 512-wide j-segment; partials committed via atomicAdd.
__global__ __launch_bounds__(256) void lj_kernel(const float* __restrict__ q,
                                                 float* __restrict__ dp) {
    __shared__ float qs[SEG * 3];

    const int jseg  = blockIdx.x;
    const int itile = blockIdx.y;
    const int b     = blockIdx.z;

    const float* qb = q + (size_t)b * NPART * 3;

    // Stage this block's j-segment into LDS (coalesced: 1536 contiguous floats)
    const int jbase = jseg * SEG * 3;
    for (int k = threadIdx.x; k < SEG * 3; k += TI) {
        qs[k] = qb[jbase + k];
    }
    __syncthreads();

    const int i = itile * TI + threadIdx.x;
    const float qx = qb[i * 3 + 0];
    const float qy = qb[i * 3 + 1];
    const float qz = qb[i * 3 + 2];

    float fx = 0.0f, fy = 0.0f, fz = 0.0f;

    // j is wave-uniform -> LDS reads are broadcasts (conflict-free)
    #pragma unroll 4
    for (int j = 0; j < SEG; ++j) {
        const float dx = qx - qs[j * 3 + 0];
        const float dy = qy - qs[j * 3 + 1];
        const float dz = qz - qs[j * 3 + 2];
        const float r2 = dx * dx + dy * dy + dz * dz;
        // mask r2>0 excludes i==j (exactly 0.0f) just like the reference
        const float inv = (r2 > 0.0f) ? (1.0f / r2) : 0.0f;
        const float s6 = inv * inv * inv;               // sigma = 1
        const float coeff = 24.0f * inv * s6 * (2.0f * s6 - 1.0f);
        fx = fmaf(coeff, dx, fx);
        fy = fmaf(coeff, dy, fy);
        fz = fmaf(coeff, dz, fz);
    }

    float* out = &dp[((size_t)b * NPART + i) * 3];
    atomicAdd(&out[0], fx);
    atomicAdd(&out[1], fy);
    atomicAdd(&out[2], fz);
}

extern "C" void kernel_launch(void* const* d_in, const int* in_sizes, int n_in,
                              void* d_out, int out_size, void* d_ws, size_t ws_size,
                              hipStream_t stream) {
    const float* q = (const float*)d_in[0];
    const float* p = (const float*)d_in[1];
    const float* m = (const float*)d_in[2];
    // d_in[3] = t, unused by the reference outputs

    const int n_elem = BATCH * NPART * 3;   // 24576 per output tensor
    float* dq_out = (float*)d_out;          // first output: dq
    float* dp_out = (float*)d_out + n_elem; // second output: dp

    // dp is accumulated atomically -> must start from zero every call
    hipMemsetAsync(dp_out, 0, (size_t)n_elem * sizeof(float), stream);

    dq_kernel<<<(n_elem + 255) / 256, 256, 0, stream>>>(p, m, dq_out, n_elem);

    dim3 grid(JSEGS, NPART / TI, BATCH);
    lj_kernel<<<grid, TI, 0, stream>>>(q, dp_out);
}

// Round 2
// 27.410 us; speedup vs baseline: 1.7057x; 1.7057x over previous
//
#include <hip/hip_runtime.h>

// Problem constants (match reference setup_inputs)
#define BATCH 2
#define NPART 4096
#define TI 256                 // i-particles per block (1 per thread)
#define JSEGS 32               // j-segments -> 32*16*2 = 1024 blocks (4/CU)
#define SEG (NPART / JSEGS)    // 128 j-particles staged in LDS per block

// Lennard-Jones pair forces: dp[b,i,:] = sum_j coeff(i,j) * (q_i - q_j)
// coeff = 24*eps*inv_r2*s6*(2*s6-1) = inv*s6*(48*s6-24) with eps=sigma=1
// Grid: (JSEGS, NPART/TI, BATCH), block TI=256. Partials via atomicAdd.
// Blocks with jseg==0 also emit dq = p/m for their i-range (each (b,i) once).
__global__ __launch_bounds__(256) void lj_kernel(const float* __restrict__ q,
                                                 const float* __restrict__ p,
                                                 const float* __restrict__ m,
                                                 float* __restrict__ dq,
                                                 float* __restrict__ dp) {
    __shared__ float qs[SEG * 3];

    const int jseg  = blockIdx.x;
    const int itile = blockIdx.y;
    const int b     = blockIdx.z;

    const float* qb = q + (size_t)b * NPART * 3;

    // Stage this block's j-segment into LDS (coalesced, 384 contiguous floats)
    const int jbase = jseg * SEG * 3;
    for (int k = threadIdx.x; k < SEG * 3; k += TI) {
        qs[k] = qb[jbase + k];
    }
    __syncthreads();

    const int i = itile * TI + threadIdx.x;
    const float qx = qb[i * 3 + 0];
    const float qy = qb[i * 3 + 1];
    const float qz = qb[i * 3 + 2];

    float fx = 0.0f, fy = 0.0f, fz = 0.0f;

    // j is wave-uniform -> LDS reads are broadcasts (conflict-free)
    #pragma unroll 8
    for (int j = 0; j < SEG; ++j) {
        const float dx = qx - qs[j * 3 + 0];
        const float dy = qy - qs[j * 3 + 1];
        const float dz = qz - qs[j * 3 + 2];
        const float r2 = fmaf(dz, dz, fmaf(dy, dy, dx * dx));
        // mask r2>0 excludes i==j (exactly 0.0f) just like the reference.
        // v_rcp_f32 approx: rel err ~1e-7 -> ~1e-6 after s12; threshold is ~2e-2 rel.
        const float rcp = __builtin_amdgcn_rcpf(r2);
        const float inv = (r2 > 0.0f) ? rcp : 0.0f;
        const float s6 = inv * inv * inv;                    // sigma = 1
        const float c1 = fmaf(48.0f, s6, -24.0f);            // 48*s6 - 24
        const float coeff = (inv * s6) * c1;                 // 24*inv*s6*(2*s6-1)
        fx = fmaf(coeff, dx, fx);
        fy = fmaf(coeff, dy, fy);
        fz = fmaf(coeff, dz, fz);
    }

    float* out = &dp[((size_t)b * NPART + i) * 3];
    atomicAdd(&out[0], fx);
    atomicAdd(&out[1], fy);
    atomicAdd(&out[2], fz);

    // dq = p/m, emitted exactly once per (b,i) by the jseg==0 blocks
    if (jseg == 0) {
        const size_t base = ((size_t)b * NPART + i) * 3;
        const float invm = 1.0f / m[(size_t)b * NPART + i];  // exact IEEE div, tiny count
        dq[base + 0] = p[base + 0] * invm;
        dq[base + 1] = p[base + 1] * invm;
        dq[base + 2] = p[base + 2] * invm;
    }
}

extern "C" void kernel_launch(void* const* d_in, const int* in_sizes, int n_in,
                              void* d_out, int out_size, void* d_ws, size_t ws_size,
                              hipStream_t stream) {
    const float* q = (const float*)d_in[0];
    const float* p = (const float*)d_in[1];
    const float* m = (const float*)d_in[2];
    // d_in[3] = t, unused by the reference outputs

    const int n_elem = BATCH * NPART * 3;   // 24576 per output tensor
    float* dq_out = (float*)d_out;          // first output: dq
    float* dp_out = (float*)d_out + n_elem; // second output: dp

    // dp is accumulated atomically -> must start from zero every call
    hipMemsetAsync(dp_out, 0, (size_t)n_elem * sizeof(float), stream);

    dim3 grid(JSEGS, NPART / TI, BATCH);
    lj_kernel<<<grid, TI, 0, stream>>>(q, p, m, dq_out, dp_out);
}

// Round 3
// 22.765 us; speedup vs baseline: 2.0537x; 1.2040x over previous
//
#include <hip/hip_runtime.h>

// Problem constants (match reference setup_inputs)
#define BATCH 2
#define NPART 4096
#define TI 256                 // i-particles per block (1 per thread)
#define JSEGS 32               // -> 32*16*2 = 1024 blocks (4/CU, 4 waves/SIMD)
#define SEG (NPART / JSEGS)    // 128 j-particles staged in LDS per block

typedef float v2f __attribute__((ext_vector_type(2)));

// Per-thread inner loop over this block's j-segment, 2 j's at a time in
// packed-f32 registers. MASKED=true only for blocks whose j-range can
// contain j==i (the diagonal); others skip the r2>0 guard entirely.
template <bool MASKED>
__device__ inline void lj_inner(const float* qsx, const float* qsy, const float* qsz,
                                float qx, float qy, float qz,
                                float& Fx, float& Fy, float& Fz) {
    const v2f* xs = (const v2f*)qsx;
    const v2f* ys = (const v2f*)qsy;
    const v2f* zs = (const v2f*)qsz;

    v2f fx = (v2f)0.0f, fy = (v2f)0.0f, fz = (v2f)0.0f;

    #pragma unroll 4
    for (int jj = 0; jj < SEG / 2; ++jj) {
        const v2f dx = (v2f)qx - xs[jj];
        const v2f dy = (v2f)qy - ys[jj];
        const v2f dz = (v2f)qz - zs[jj];
        v2f r2 = dx * dx;
        r2 = __builtin_elementwise_fma(dy, dy, r2);
        r2 = __builtin_elementwise_fma(dz, dz, r2);
        v2f inv;
        if (MASKED) {
            // r2==0.0f exactly <=> i==j (reference's mask semantics)
            inv.x = (r2.x > 0.0f) ? __builtin_amdgcn_rcpf(r2.x) : 0.0f;
            inv.y = (r2.y > 0.0f) ? __builtin_amdgcn_rcpf(r2.y) : 0.0f;
        } else {
            inv.x = __builtin_amdgcn_rcpf(r2.x);
            inv.y = __builtin_amdgcn_rcpf(r2.y);
        }
        const v2f inv2 = inv * inv;
        const v2f s6 = inv2 * inv;                                   // sigma = 1
        const v2f c1 = __builtin_elementwise_fma((v2f)48.0f, s6, (v2f)(-24.0f));
        const v2f coeff = (inv * s6) * c1;  // 24*inv*s6*(2*s6-1)
        fx = __builtin_elementwise_fma(coeff, dx, fx);
        fy = __builtin_elementwise_fma(coeff, dy, fy);
        fz = __builtin_elementwise_fma(coeff, dz, fz);
    }

    Fx = fx.x + fx.y;
    Fy = fy.x + fy.y;
    Fz = fz.x + fz.y;
}

// Grid: (JSEGS, NPART/TI, BATCH), block TI=256. Partials via atomicAdd.
// jseg==0 blocks also emit dq = p/m for their i-range.
__global__ __launch_bounds__(256) void lj_kernel(const float* __restrict__ q,
                                                 const float* __restrict__ p,
                                                 const float* __restrict__ m,
                                                 float* __restrict__ dq,
                                                 float* __restrict__ dp) {
    __shared__ float qsx[SEG], qsy[SEG], qsz[SEG];

    const int jseg  = blockIdx.x;
    const int itile = blockIdx.y;
    const int b     = blockIdx.z;

    const float* qb = q + (size_t)b * NPART * 3;

    // Stage j-segment into SoA LDS (tiny: 1.5 KB)
    const int jbase = jseg * SEG * 3;
    for (int k = threadIdx.x; k < SEG; k += TI) {
        qsx[k] = qb[jbase + 3 * k + 0];
        qsy[k] = qb[jbase + 3 * k + 1];
        qsz[k] = qb[jbase + 3 * k + 2];
    }
    __syncthreads();

    const int i = itile * TI + threadIdx.x;
    const float qx = qb[i * 3 + 0];
    const float qy = qb[i * 3 + 1];
    const float qz = qb[i * 3 + 2];

    float Fx, Fy, Fz;
    // Diagonal possible iff j-range overlaps i-range: jseg in {2*itile, 2*itile+1}
    const bool diag = (jseg >> 1) == itile;
    if (diag) {
        lj_inner<true >(qsx, qsy, qsz, qx, qy, qz, Fx, Fy, Fz);
    } else {
        lj_inner<false>(qsx, qsy, qsz, qx, qy, qz, Fx, Fy, Fz);
    }

    float* out = &dp[((size_t)b * NPART + i) * 3];
    atomicAdd(&out[0], Fx);
    atomicAdd(&out[1], Fy);
    atomicAdd(&out[2], Fz);

    // dq = p/m, emitted exactly once per (b,i) by the jseg==0 blocks
    if (jseg == 0) {
        const size_t base = ((size_t)b * NPART + i) * 3;
        const float invm = 1.0f / m[(size_t)b * NPART + i];  // exact IEEE div, tiny count
        dq[base + 0] = p[base + 0] * invm;
        dq[base + 1] = p[base + 1] * invm;
        dq[base + 2] = p[base + 2] * invm;
    }
}

extern "C" void kernel_launch(void* const* d_in, const int* in_sizes, int n_in,
                              void* d_out, int out_size, void* d_ws, size_t ws_size,
                              hipStream_t stream) {
    const float* q = (const float*)d_in[0];
    const float* p = (const float*)d_in[1];
    const float* m = (const float*)d_in[2];
    // d_in[3] = t, unused by the reference outputs

    const int n_elem = BATCH * NPART * 3;   // 24576 per output tensor
    float* dq_out = (float*)d_out;          // first output: dq
    float* dp_out = (float*)d_out + n_elem; // second output: dp

    // dp is accumulated atomically -> must start from zero every call
    hipMemsetAsync(dp_out, 0, (size_t)n_elem * sizeof(float), stream);

    dim3 grid(JSEGS, NPART / TI, BATCH);
    lj_kernel<<<grid, TI, 0, stream>>>(q, p, m, dq_out, dp_out);
}